// Round 10
// baseline (182.779 us; speedup 1.0000x reference)
//
#include <hip/hip_runtime.h>

typedef __attribute__((ext_vector_type(8))) short bf16x8;
typedef __attribute__((ext_vector_type(4))) float f32x4;
typedef __attribute__((ext_vector_type(16))) float f32x16;
typedef unsigned short u16;
typedef unsigned int u32;

#define SEQ 2048
#define NHEAD 16
#define EXP2_SCALE 0.045084219f  // (1024^-0.5) * log2(e), folded into Q at gemm_qkv epilogue

__device__ __forceinline__ u16 f2bf(float f){
  u32 u = __builtin_bit_cast(u32, f);
  u += 0x7FFFu + ((u >> 16) & 1u);   // RNE
  return (u16)(u >> 16);
}

// async global->LDS, 16B per lane; LDS dest = uniform base + lane*16
__device__ __forceinline__ void gl16(const u16* g, u16* l){
  __builtin_amdgcn_global_load_lds(
      (__attribute__((address_space(1))) void*)(unsigned long long)(const void*)g,
      (__attribute__((address_space(3))) void*)(unsigned)(unsigned long long)(const void*)l,
      16, 0, 0);
}

// ---------------- fused prep: x->bf16, w_qkv^T->bf16, w_out^T->bf16 ----------------
__global__ __launch_bounds__(256) void prep(const float* __restrict__ x,
                                            const float* __restrict__ w_qkv,
                                            const float* __restrict__ w_out,
                                            u16* __restrict__ xb,
                                            u16* __restrict__ wqkvT,
                                            u16* __restrict__ woutT){
  __shared__ u16 t[32][33];
  const int bid = blockIdx.x;
  if (bid < 4096){
    int i = (bid * 256 + threadIdx.x) << 2;
    float4 v = *(const float4*)&x[i];
    ushort4 o;
    o.x = f2bf(v.x); o.y = f2bf(v.y); o.z = f2bf(v.z); o.w = f2bf(v.w);
    *(ushort4*)&xb[i] = o;
    return;
  }
  const float* src; u16* dst; int R, C, bx, by;
  if (bid < 7168){ int tt = bid - 4096; src = w_qkv; dst = wqkvT; R = 1024; C = 3072; bx = tt % 96; by = tt / 96; }
  else           { int tt = bid - 7168; src = w_out; dst = woutT; R = 1024; C = 1024; bx = tt % 32; by = tt / 32; }
  const int c0 = bx << 5, r0 = by << 5;
  const int tx = threadIdx.x & 31, tg = threadIdx.x >> 5;
  #pragma unroll
  for (int i = 0; i < 4; i++){
    int r = (tg << 2) + i;
    t[r][tx] = f2bf(src[(size_t)(r0 + r) * C + (c0 + tx)]);
  }
  __syncthreads();
  #pragma unroll
  for (int i = 0; i < 4; i++){
    int c = (tg << 2) + i;
    dst[(size_t)(c0 + c) * R + (r0 + tx)] = t[tx][c];
  }
}

// ---------------- GEMM1: xb[4096,1024] @ wqkvT -> Q/K/Vt (bf16), BK=64 ----------------
__global__ __launch_bounds__(256) void gemm_qkv(const u16* __restrict__ A,
                                                const u16* __restrict__ Bt,
                                                u16* __restrict__ Qo,
                                                u16* __restrict__ Ko,
                                                u16* __restrict__ Vto){
  __shared__ u16 As[128 * 64];   // 16 KB, chunk c of row r at slot c^(r&7)
  __shared__ u16 Bs[128 * 64];
  const int tid = threadIdx.x;
  const int lane = tid & 63, wid = tid >> 6;
  const int l15 = lane & 15, quad = lane >> 4;
  const int wm = wid >> 1, wn = wid & 1;
  const int bid = blockIdx.x;
  const int xcd = bid & 7, t8 = bid >> 3;          // t8 in [0,96)
  const int bm = ((xcd << 2) + (t8 & 3)) << 7;     // M strip
  const int bn = (t8 >> 2) << 7;                   // N strip (outer)
  const int qkv_idx = bn >> 10;

  const int lr = lane >> 3;
  const int cc = (lane & 7) ^ lr;
  const u16* gA0 = A  + (size_t)(bm + wid * 32 + lr) * 1024 + (cc << 3);
  const u16* gB0 = Bt + (size_t)(bn + wid * 32 + lr) * 1024 + (cc << 3);
  u16* lA0 = &As[wid * 2048];
  u16* lB0 = &Bs[wid * 2048];

  f32x4 acc[4][4];
  #pragma unroll
  for (int i = 0; i < 4; i++)
    #pragma unroll
    for (int j = 0; j < 4; j++) acc[i][j] = (f32x4){0.f, 0.f, 0.f, 0.f};

  for (int k0 = 0; k0 < 1024; k0 += 64){
    #pragma unroll
    for (int t = 0; t < 4; t++){
      gl16(gA0 + k0 + t * 8192, lA0 + t * 512);
      gl16(gB0 + k0 + t * 8192, lB0 + t * 512);
    }
    __syncthreads();
    #pragma unroll
    for (int hf = 0; hf < 2; hf++){
      bf16x8 af[4], bfr[4];
      #pragma unroll
      for (int mt = 0; mt < 4; mt++){
        int row = wm * 64 + mt * 16 + l15;
        af[mt] = *(const bf16x8*)&As[row * 64 + (((hf * 4 + quad) ^ (row & 7)) << 3)];
      }
      #pragma unroll
      for (int nt = 0; nt < 4; nt++){
        int row = wn * 64 + nt * 16 + l15;
        bfr[nt] = *(const bf16x8*)&Bs[row * 64 + (((hf * 4 + quad) ^ (row & 7)) << 3)];
      }
      #pragma unroll
      for (int mt = 0; mt < 4; mt++)
        #pragma unroll
        for (int nt = 0; nt < 4; nt++)   // swapped operands -> transposed C
          acc[mt][nt] = __builtin_amdgcn_mfma_f32_16x16x32_bf16(bfr[nt], af[mt], acc[mt][nt], 0, 0, 0);
    }
    __syncthreads();
  }

  if (qkv_idx != 2){
    const float qs = (qkv_idx == 0) ? EXP2_SCALE : 1.0f;
    u16* dst = (qkv_idx == 0) ? Qo : Ko;
    #pragma unroll
    for (int mt = 0; mt < 4; mt++){
      int xr = bm + wm * 64 + mt * 16 + l15;      // x row (lane-dim)
      int b = xr >> 11, pos = xr & 2047;
      #pragma unroll
      for (int nt = 0; nt < 4; nt++){
        int c0 = bn + wn * 64 + nt * 16 + quad * 4;   // weight col base (reg-dim)
        int head = (c0 & 1023) >> 6, hd0 = c0 & 63;
        size_t bhh = ((size_t)(b * NHEAD + head)) << 17;
        ushort4 w;
        w.x = f2bf(acc[mt][nt][0] * qs); w.y = f2bf(acc[mt][nt][1] * qs);
        w.z = f2bf(acc[mt][nt][2] * qs); w.w = f2bf(acc[mt][nt][3] * qs);
        *(ushort4*)&dst[bhh + ((size_t)pos << 6) + hd0] = w;
      }
    }
  } else {
    #pragma unroll
    for (int mt = 0; mt < 4; mt++){
      int xr = bm + wm * 64 + mt * 16 + l15;
      int b = xr >> 11, pos = xr & 2047;
      #pragma unroll
      for (int nt = 0; nt < 4; nt++){
        #pragma unroll
        for (int r = 0; r < 4; r++){
          int c = bn + wn * 64 + nt * 16 + quad * 4 + r;
          int head = (c & 1023) >> 6, hd_i = c & 63;
          size_t bhh = ((size_t)(b * NHEAD + head)) << 17;
          Vto[bhh + ((size_t)hd_i << 11) + pos] = f2bf(acc[mt][nt][r]);  // V^T [hd][seq]
        }
      }
    }
  }
}

// ---------------- flash attention, causal, 32x32x16 MFMA, no P in LDS ----------------
// 128-thread blocks (2 waves x 32 q-rows), grid 1024 heavy-first. LDS = K+V only (32KB).
// P layout transform C->B done with 4 shfl_xor(32) + 4 selects per 16-kv slice.
__global__ __launch_bounds__(128) void attn_kernel(const u16* __restrict__ Q,
                                                   const u16* __restrict__ K,
                                                   const u16* __restrict__ Vt,
                                                   u16* __restrict__ Oo){
  __shared__ u16 Ks[128 * 64];       // [kv][d] chunk c at slot c^(row&7)
  __shared__ u16 Vts[64 * 128];      // [d][kv] chunk c at slot c^(row&15)
  const int tid = threadIdx.x;
  const int lane = tid & 63, wid = tid >> 6;   // wid 0..1
  const int l31 = lane & 31, h = lane >> 5;
  const bool hb = (h != 0);
  const int bh = blockIdx.x & 31;
  const int qt = 31 - (blockIdx.x >> 5);       // heavy blocks dispatch first
  const size_t base = ((size_t)bh) << 17;      // (b*16+head)*2048*64
  const int b = bh >> 4, head = bh & 15;

  // Q fragments (B-operand: n=l31 -> q row, k = ks*16 + h*8 + j), loop-invariant
  const int qpos = (qt << 6) + wid * 32 + l31;
  const u16* qsrc = Q + base + ((size_t)qpos << 6) + h * 8;
  bf16x8 bq[4];
  #pragma unroll
  for (int ks = 0; ks < 4; ks++) bq[ks] = *(const bf16x8*)(qsrc + ks * 16);

  // K staging: wave covers K rows [wid*64, wid*64+64), 8 DMAs x 8 rows
  const int lrK = lane >> 3;
  const int cK = (lane & 7) ^ lrK;
  const u16* gK0 = K + base + ((size_t)(wid * 64 + lrK) << 6) + (cK << 3);
  u16* lK = &Ks[wid * 4096];
  // V staging: wave covers V rows [wid*32, wid*32+32), 8 DMAs x 4 rows (t>=4: +16 rows)
  const u16* gV[4];
  #pragma unroll
  for (int t = 0; t < 4; t++){
    int rv = wid * 32 + t * 4 + (lane >> 4);
    int cv = (lane & 15) ^ (rv & 15);
    gV[t] = Vt + base + (size_t)rv * 2048 + (cv << 3);
  }
  u16* lV = &Vts[wid * 4096];

  f32x16 o[2];
  #pragma unroll
  for (int i = 0; i < 2; i++)
    #pragma unroll
    for (int r = 0; r < 16; r++) o[i][r] = 0.f;
  float lsum = 0.f;
  const int jt_max = qt >> 1;

  auto kv_iter = [&](const int jt, const bool diag) __attribute__((always_inline)) {
    const u16* gk = gK0 + (size_t)jt * 8192;
    #pragma unroll
    for (int t = 0; t < 8; t++) gl16(gk + t * 512, lK + t * 512);
    #pragma unroll
    for (int t = 0; t < 8; t++) gl16(gV[t & 3] + (t >> 2) * 32768 + (jt << 7), lV + t * 512);
    __syncthreads();

    #pragma unroll
    for (int mtp = 0; mtp < 4; mtp += 2){
      // S^T = K * Q^T for kv tiles mtp, mtp+1 (32 kv each x wave's 32 q)
      f32x16 st[2];
      #pragma unroll
      for (int u = 0; u < 2; u++)
        #pragma unroll
        for (int r = 0; r < 16; r++) st[u][r] = 0.f;
      #pragma unroll
      for (int ks = 0; ks < 4; ks++){
        #pragma unroll
        for (int u = 0; u < 2; u++){
          int row = (mtp + u) * 32 + l31;
          bf16x8 ak = *(const bf16x8*)&Ks[row * 64 + (((ks * 2 + h) ^ (row & 7)) << 3)];
          st[u] = __builtin_amdgcn_mfma_f32_32x32x16_bf16(ak, bq[ks], st[u], 0, 0, 0);
        }
      }
      #pragma unroll
      for (int u = 0; u < 2; u++){
        const int mt = mtp + u;
        // p = exp2(st) (Q pre-scaled); mask only on peeled diagonal call
        float pr[16];
        #pragma unroll
        for (int r = 0; r < 16; r++){
          float w = st[u][r];
          if (diag){
            int kv = (jt << 7) + mt * 32 + (r & 3) + 8 * (r >> 2) + 4 * h;
            if (kv > qpos) w = -INFINITY;
          }
          pr[r] = __builtin_amdgcn_exp2f(w);
          lsum += pr[r];
        }
        // pack pairs -> u32 bf16x2 (round-half-up + v_perm); group g: rows 8g+{0..3}+4h
        u32 pk[8];
        #pragma unroll
        for (int g = 0; g < 4; g++){
          u32 a0 = __builtin_bit_cast(u32, pr[4*g+0]) + 0x8000u;
          u32 a1 = __builtin_bit_cast(u32, pr[4*g+1]) + 0x8000u;
          u32 a2 = __builtin_bit_cast(u32, pr[4*g+2]) + 0x8000u;
          u32 a3 = __builtin_bit_cast(u32, pr[4*g+3]) + 0x8000u;
          pk[2*g]   = __builtin_amdgcn_perm(a1, a0, 0x07060302u);
          pk[2*g+1] = __builtin_amdgcn_perm(a3, a2, 0x07060302u);
        }
        // per 16-kv slice: build B-frag via lane-pair exchange, then PV
        #pragma unroll
        for (int half = 0; half < 2; half++){
          u32 A0 = pk[4*half+0], A1 = pk[4*half+1];
          u32 B0 = pk[4*half+2], B1 = pk[4*half+3];
          u32 sA0 = (u32)__shfl_xor((int)A0, 32);
          u32 sA1 = (u32)__shfl_xor((int)A1, 32);
          u32 sB0 = (u32)__shfl_xor((int)B0, 32);
          u32 sB1 = (u32)__shfl_xor((int)B1, 32);
          uint4 wv;
          wv.x = hb ? sB0 : A0;
          wv.y = hb ? sB1 : A1;
          wv.z = hb ? B0  : sA0;
          wv.w = hb ? B1  : sA1;
          bf16x8 bp = __builtin_bit_cast(bf16x8, wv);
          const int s = mt * 2 + half;
          #pragma unroll
          for (int dt = 0; dt < 2; dt++){
            int dr = dt * 32 + l31;
            bf16x8 av = *(const bf16x8*)&Vts[dr * 128 + (((s * 2 + h) ^ (dr & 15)) << 3)];
            o[dt] = __builtin_amdgcn_mfma_f32_32x32x16_bf16(av, bp, o[dt], 0, 0, 0);
          }
        }
      }
    }
    __syncthreads();
  };

  for (int jt = 0; jt < jt_max; jt++) kv_iter(jt, false);
  kv_iter(jt_max, true);

  // column sum lives in a lane pair (q,h),(q,h^1)
  lsum += __shfl_xor(lsum, 32);
  float inv = 1.f / lsum;
  const size_t orow = (size_t)((b << 11) + qpos) * 1024 + head * 64;
  #pragma unroll
  for (int dt = 0; dt < 2; dt++){
    #pragma unroll
    for (int g = 0; g < 4; g++){
      ushort4 w;
      w.x = f2bf(o[dt][4*g+0] * inv); w.y = f2bf(o[dt][4*g+1] * inv);
      w.z = f2bf(o[dt][4*g+2] * inv); w.w = f2bf(o[dt][4*g+3] * inv);
      *(ushort4*)&Oo[orow + dt * 32 + 8 * g + 4 * h] = w;
    }
  }
}

// ---------------- GEMM2: attn[4096,1024](bf16) @ woutT + b_out -> out (fp32), BK=64 ----------------
__global__ __launch_bounds__(256) void gemm_out(const u16* __restrict__ A,
                                                const u16* __restrict__ Bt,
                                                const float* __restrict__ bias,
                                                float* __restrict__ out){
  __shared__ u16 As[128 * 64];
  __shared__ u16 Bs[128 * 64];
  const int tid = threadIdx.x;
  const int lane = tid & 63, wid = tid >> 6;
  const int l15 = lane & 15, quad = lane >> 4;
  const int wm = wid >> 1, wn = wid & 1;
  const int bid = blockIdx.x;
  const int xcd = bid & 7, t8 = bid >> 3;          // t8 in [0,32)
  const int bm = ((xcd << 2) + (t8 & 3)) << 7;
  const int bn = (t8 >> 2) << 7;                   // [0,1024)

  const int lr = lane >> 3;
  const int cc = (lane & 7) ^ lr;
  const u16* gA0 = A  + (size_t)(bm + wid * 32 + lr) * 1024 + (cc << 3);
  const u16* gB0 = Bt + (size_t)(bn + wid * 32 + lr) * 1024 + (cc << 3);
  u16* lA0 = &As[wid * 2048];
  u16* lB0 = &Bs[wid * 2048];

  f32x4 acc[4][4];
  #pragma unroll
  for (int i = 0; i < 4; i++)
    #pragma unroll
    for (int j = 0; j < 4; j++) acc[i][j] = (f32x4){0.f, 0.f, 0.f, 0.f};

  for (int k0 = 0; k0 < 1024; k0 += 64){
    #pragma unroll
    for (int t = 0; t < 4; t++){
      gl16(gA0 + k0 + t * 8192, lA0 + t * 512);
      gl16(gB0 + k0 + t * 8192, lB0 + t * 512);
    }
    __syncthreads();
    #pragma unroll
    for (int hf = 0; hf < 2; hf++){
      bf16x8 af[4], bfr[4];
      #pragma unroll
      for (int mt = 0; mt < 4; mt++){
        int row = wm * 64 + mt * 16 + l15;
        af[mt] = *(const bf16x8*)&As[row * 64 + (((hf * 4 + quad) ^ (row & 7)) << 3)];
      }
      #pragma unroll
      for (int nt = 0; nt < 4; nt++){
        int row = wn * 64 + nt * 16 + l15;
        bfr[nt] = *(const bf16x8*)&Bs[row * 64 + (((hf * 4 + quad) ^ (row & 7)) << 3)];
      }
      #pragma unroll
      for (int mt = 0; mt < 4; mt++)
        #pragma unroll
        for (int nt = 0; nt < 4; nt++)
          acc[mt][nt] = __builtin_amdgcn_mfma_f32_16x16x32_bf16(bfr[nt], af[mt], acc[mt][nt], 0, 0, 0);
    }
    __syncthreads();
  }

  #pragma unroll
  for (int nt = 0; nt < 4; nt++){
    int c0 = bn + wn * 64 + nt * 16 + quad * 4;    // col base (reg-dim)
    float4 bv = *(const float4*)&bias[c0];
    #pragma unroll
    for (int mt = 0; mt < 4; mt++){
      int row = bm + wm * 64 + mt * 16 + l15;      // row (lane-dim)
      float4 w;
      w.x = acc[mt][nt][0] + bv.x; w.y = acc[mt][nt][1] + bv.y;
      w.z = acc[mt][nt][2] + bv.z; w.w = acc[mt][nt][3] + bv.w;
      *(float4*)&out[(size_t)row * 1024 + c0] = w;
    }
  }
}

extern "C" void kernel_launch(void* const* d_in, const int* in_sizes, int n_in,
                              void* d_out, int out_size, void* d_ws, size_t ws_size,
                              hipStream_t stream){
  const float* x     = (const float*)d_in[0];
  const float* w_qkv = (const float*)d_in[1];
  const float* w_out = (const float*)d_in[2];
  const float* b_out = (const float*)d_in[3];
  float* out = (float*)d_out;

  char* ws = (char*)d_ws;
  u16* xb    = (u16*)(ws);                  // [4096][1024] bf16   8 MB
  u16* wqkvT = (u16*)(ws + (8u  << 20));    // [3072][1024]        6 MB
  u16* woutT = (u16*)(ws + (14u << 20));    // [1024][1024]        2 MB
  u16* Qb    = (u16*)(ws + (16u << 20));    // [2,16,2048,64]      8 MB
  u16* Kb    = (u16*)(ws + (24u << 20));    // 8 MB
  u16* Vtb   = (u16*)(ws + (32u << 20));    // [2,16,64,2048]      8 MB
  u16* attn  = (u16*)(ws + (40u << 20));    // [4096][1024]        8 MB

  prep<<<8192, 256, 0, stream>>>(x, w_qkv, w_out, xb, wqkvT, woutT);
  gemm_qkv<<<768, 256, 0, stream>>>(xb, wqkvT, Qb, Kb, Vtb);
  attn_kernel<<<dim3(1024), 128, 0, stream>>>(Qb, Kb, Vtb, attn);
  gemm_out<<<256, 256, 0, stream>>>(attn, woutT, b_out, out);
}

// Round 11
// 176.052 us; speedup vs baseline: 1.0382x; 1.0382x over previous
//
#include <hip/hip_runtime.h>

typedef __attribute__((ext_vector_type(8))) short bf16x8;
typedef __attribute__((ext_vector_type(4))) float f32x4;
typedef unsigned short u16;
typedef unsigned int u32;

#define SEQ 2048
#define NHEAD 16
#define EXP2_SCALE 0.045084219f  // (1024^-0.5) * log2(e), folded into Q at gemm_qkv epilogue

__device__ __forceinline__ u16 f2bf(float f){
  u32 u = __builtin_bit_cast(u32, f);
  u += 0x7FFFu + ((u >> 16) & 1u);   // RNE
  return (u16)(u >> 16);
}

// async global->LDS, 16B per lane; LDS dest = uniform base + lane*16
__device__ __forceinline__ void gl16(const u16* g, u16* l){
  __builtin_amdgcn_global_load_lds(
      (__attribute__((address_space(1))) void*)(unsigned long long)(const void*)g,
      (__attribute__((address_space(3))) void*)(unsigned)(unsigned long long)(const void*)l,
      16, 0, 0);
}

// ---------------- fused prep: x->bf16, w_qkv^T->bf16, w_out^T->bf16 ----------------
__global__ __launch_bounds__(256) void prep(const float* __restrict__ x,
                                            const float* __restrict__ w_qkv,
                                            const float* __restrict__ w_out,
                                            u16* __restrict__ xb,
                                            u16* __restrict__ wqkvT,
                                            u16* __restrict__ woutT){
  __shared__ u16 t[32][33];
  const int bid = blockIdx.x;
  if (bid < 4096){
    int i = (bid * 256 + threadIdx.x) << 2;
    float4 v = *(const float4*)&x[i];
    ushort4 o;
    o.x = f2bf(v.x); o.y = f2bf(v.y); o.z = f2bf(v.z); o.w = f2bf(v.w);
    *(ushort4*)&xb[i] = o;
    return;
  }
  const float* src; u16* dst; int R, C, bx, by;
  if (bid < 7168){ int tt = bid - 4096; src = w_qkv; dst = wqkvT; R = 1024; C = 3072; bx = tt % 96; by = tt / 96; }
  else           { int tt = bid - 7168; src = w_out; dst = woutT; R = 1024; C = 1024; bx = tt % 32; by = tt / 32; }
  const int c0 = bx << 5, r0 = by << 5;
  const int tx = threadIdx.x & 31, tg = threadIdx.x >> 5;
  #pragma unroll
  for (int i = 0; i < 4; i++){
    int r = (tg << 2) + i;
    t[r][tx] = f2bf(src[(size_t)(r0 + r) * C + (c0 + tx)]);
  }
  __syncthreads();
  #pragma unroll
  for (int i = 0; i < 4; i++){
    int c = (tg << 2) + i;
    dst[(size_t)(c0 + c) * R + (r0 + tx)] = t[tx][c];
  }
}

// ---------------- GEMM1: xb[4096,1024] @ wqkvT -> Q/K/Vt (bf16), BK=64 ----------------
__global__ __launch_bounds__(256) void gemm_qkv(const u16* __restrict__ A,
                                                const u16* __restrict__ Bt,
                                                u16* __restrict__ Qo,
                                                u16* __restrict__ Ko,
                                                u16* __restrict__ Vto){
  __shared__ u16 As[128 * 64];   // 16 KB, chunk c of row r at slot c^(r&7)
  __shared__ u16 Bs[128 * 64];
  const int tid = threadIdx.x;
  const int lane = tid & 63, wid = tid >> 6;
  const int l15 = lane & 15, quad = lane >> 4;
  const int wm = wid >> 1, wn = wid & 1;
  const int bid = blockIdx.x;
  const int xcd = bid & 7, t8 = bid >> 3;          // t8 in [0,96)
  const int bm = ((xcd << 2) + (t8 & 3)) << 7;     // M strip
  const int bn = (t8 >> 2) << 7;                   // N strip (outer)
  const int qkv_idx = bn >> 10;

  const int lr = lane >> 3;
  const int cc = (lane & 7) ^ lr;
  const u16* gA0 = A  + (size_t)(bm + wid * 32 + lr) * 1024 + (cc << 3);
  const u16* gB0 = Bt + (size_t)(bn + wid * 32 + lr) * 1024 + (cc << 3);
  u16* lA0 = &As[wid * 2048];
  u16* lB0 = &Bs[wid * 2048];

  f32x4 acc[4][4];
  #pragma unroll
  for (int i = 0; i < 4; i++)
    #pragma unroll
    for (int j = 0; j < 4; j++) acc[i][j] = (f32x4){0.f, 0.f, 0.f, 0.f};

  for (int k0 = 0; k0 < 1024; k0 += 64){
    #pragma unroll
    for (int t = 0; t < 4; t++){
      gl16(gA0 + k0 + t * 8192, lA0 + t * 512);
      gl16(gB0 + k0 + t * 8192, lB0 + t * 512);
    }
    __syncthreads();
    #pragma unroll
    for (int hf = 0; hf < 2; hf++){
      bf16x8 af[4], bfr[4];
      #pragma unroll
      for (int mt = 0; mt < 4; mt++){
        int row = wm * 64 + mt * 16 + l15;
        af[mt] = *(const bf16x8*)&As[row * 64 + (((hf * 4 + quad) ^ (row & 7)) << 3)];
      }
      #pragma unroll
      for (int nt = 0; nt < 4; nt++){
        int row = wn * 64 + nt * 16 + l15;
        bfr[nt] = *(const bf16x8*)&Bs[row * 64 + (((hf * 4 + quad) ^ (row & 7)) << 3)];
      }
      #pragma unroll
      for (int mt = 0; mt < 4; mt++)
        #pragma unroll
        for (int nt = 0; nt < 4; nt++)   // swapped operands -> transposed C
          acc[mt][nt] = __builtin_amdgcn_mfma_f32_16x16x32_bf16(bfr[nt], af[mt], acc[mt][nt], 0, 0, 0);
    }
    __syncthreads();
  }

  if (qkv_idx != 2){
    const float qs = (qkv_idx == 0) ? EXP2_SCALE : 1.0f;
    u16* dst = (qkv_idx == 0) ? Qo : Ko;
    #pragma unroll
    for (int mt = 0; mt < 4; mt++){
      int xr = bm + wm * 64 + mt * 16 + l15;      // x row (lane-dim)
      int b = xr >> 11, pos = xr & 2047;
      #pragma unroll
      for (int nt = 0; nt < 4; nt++){
        int c0 = bn + wn * 64 + nt * 16 + quad * 4;   // weight col base (reg-dim)
        int head = (c0 & 1023) >> 6, hd0 = c0 & 63;
        size_t bhh = ((size_t)(b * NHEAD + head)) << 17;
        ushort4 w;
        w.x = f2bf(acc[mt][nt][0] * qs); w.y = f2bf(acc[mt][nt][1] * qs);
        w.z = f2bf(acc[mt][nt][2] * qs); w.w = f2bf(acc[mt][nt][3] * qs);
        *(ushort4*)&dst[bhh + ((size_t)pos << 6) + hd0] = w;
      }
    }
  } else {
    #pragma unroll
    for (int mt = 0; mt < 4; mt++){
      int xr = bm + wm * 64 + mt * 16 + l15;
      int b = xr >> 11, pos = xr & 2047;
      #pragma unroll
      for (int nt = 0; nt < 4; nt++){
        #pragma unroll
        for (int r = 0; r < 4; r++){
          int c = bn + wn * 64 + nt * 16 + quad * 4 + r;
          int head = (c & 1023) >> 6, hd_i = c & 63;
          size_t bhh = ((size_t)(b * NHEAD + head)) << 17;
          Vto[bhh + ((size_t)hd_i << 11) + pos] = f2bf(acc[mt][nt][r]);  // V^T [hd][seq]
        }
      }
    }
  }
}

// ---------------- flash attention, causal, S^T form, fixed-base softmax ----------------
// r7 dataflow; P^T reuses the Ks region after the QK phase (extra mid-iteration barrier)
// -> LDS 32 KB -> 4 blocks/CU = 16 waves/CU, grid 1024 fully resident.
// P swizzle: 8-u16 chunk c of q-row q at slot c^(q&15).
__global__ __launch_bounds__(256) void attn_kernel(const u16* __restrict__ Q,
                                                   const u16* __restrict__ K,
                                                   const u16* __restrict__ Vt,
                                                   u16* __restrict__ Oo){
  __shared__ u16 Ks[128 * 64];       // [kv][d] chunk c at slot c^(row&7); P^T after QK
  __shared__ u16 Vts[64 * 128];      // [d][kv] chunk c at slot c^(row&15)
  const int tid = threadIdx.x;
  const int lane = tid & 63, wid = tid >> 6;
  const int l15 = lane & 15, quad = lane >> 4;
  const int bh = blockIdx.x & 31;
  const int qt = 31 - (blockIdx.x >> 5);     // heavy blocks dispatch first
  const size_t base = ((size_t)bh) << 17;    // (b*16+h)*2048*64
  const int b = bh >> 4, h = bh & 15;

  // Q fragments straight to registers (B-operand layout), loop-invariant
  const u16* qsrc = Q + base + ((size_t)((qt << 6) + wid * 16 + l15) << 6) + quad * 8;
  const bf16x8 bq0 = *(const bf16x8*)qsrc;
  const bf16x8 bq1 = *(const bf16x8*)(qsrc + 32);

  const int rK = wid * 32 + (lane >> 3);
  const int cK = (lane & 7) ^ (rK & 7);
  const u16* gK0 = K + base + ((size_t)rK << 6) + (cK << 3);
  u16* lK = &Ks[wid * 2048];
  const u16* gV[4];
  #pragma unroll
  for (int t = 0; t < 4; t++){
    int rv = wid * 16 + t * 4 + (lane >> 4);
    int cv = (lane & 15) ^ (rv & 15);
    gV[t] = Vt + base + (size_t)rv * 2048 + (cv << 3);
  }
  u16* lV = &Vts[wid * 2048];

  f32x4 o[4];
  #pragma unroll
  for (int dt = 0; dt < 4; dt++) o[dt] = (f32x4){0.f, 0.f, 0.f, 0.f};
  float lsum = 0.f;
  const int qpos = (qt << 6) + wid * 16 + l15;
  const int jt_max = qt >> 1;
  u16* Pw = &Ks[wid * 2048];                 // wave's P^T slice (reuses its Ks quarter)

  auto kv_iter = [&](const int jt, const bool diag) __attribute__((always_inline)) {
    const u16* gk = gK0 + (size_t)jt * 8192;
    #pragma unroll
    for (int t = 0; t < 4; t++) gl16(gk + t * 512, lK + t * 512);
    #pragma unroll
    for (int t = 0; t < 4; t++) gl16(gV[t] + (jt << 7), lV + t * 512);
    __syncthreads();

    // S^T = K * Q^T (reads ALL of Ks)
    f32x4 st[8];
    #pragma unroll
    for (int mt = 0; mt < 8; mt++) st[mt] = (f32x4){0.f, 0.f, 0.f, 0.f};
    #pragma unroll
    for (int mt = 0; mt < 8; mt++){
      int kvr = mt * 16 + l15;
      bf16x8 ak0 = *(const bf16x8*)&Ks[kvr * 64 + ((quad ^ (kvr & 7)) << 3)];
      st[mt] = __builtin_amdgcn_mfma_f32_16x16x32_bf16(ak0, bq0, st[mt], 0, 0, 0);
      bf16x8 ak1 = *(const bf16x8*)&Ks[kvr * 64 + (((4 + quad) ^ (kvr & 7)) << 3)];
      st[mt] = __builtin_amdgcn_mfma_f32_16x16x32_bf16(ak1, bq1, st[mt], 0, 0, 0);
    }
    __syncthreads();   // all waves done reading Ks -> safe to overwrite with P^T

    // p = exp2(st) (Q pre-scaled); causal mask only on the peeled diagonal call
    #pragma unroll
    for (int mt = 0; mt < 8; mt++){
      float pr[4];
      #pragma unroll
      for (int r = 0; r < 4; r++){
        float w = st[mt][r];
        if (diag){
          int kv = (jt << 7) + mt * 16 + quad * 4 + r;
          if (kv > qpos) w = -INFINITY;
        }
        pr[r] = __builtin_amdgcn_exp2f(w);
      }
      lsum += (pr[0] + pr[1]) + (pr[2] + pr[3]);
      u32 a0 = __builtin_bit_cast(u32, pr[0]) + 0x8000u;
      u32 a1 = __builtin_bit_cast(u32, pr[1]) + 0x8000u;
      u32 a2 = __builtin_bit_cast(u32, pr[2]) + 0x8000u;
      u32 a3 = __builtin_bit_cast(u32, pr[3]) + 0x8000u;
      uint2 pk;
      pk.x = __builtin_amdgcn_perm(a1, a0, 0x07060302u);
      pk.y = __builtin_amdgcn_perm(a3, a2, 0x07060302u);
      // row q=l15, cols mt*16+quad*4: chunk = mt*2+(quad>>1) at slot chunk^l15, half (quad&1)
      *(uint2*)&Pw[l15 * 128 + (((mt * 2 + (quad >> 1)) ^ l15) << 3) + ((quad & 1) << 2)] = pk;
    }

    // O^T += V^T * P^T
    #pragma unroll
    for (int ks = 0; ks < 4; ks++){
      bf16x8 bp = *(const bf16x8*)&Pw[l15 * 128 + (((ks * 4 + quad) ^ l15) << 3)];
      #pragma unroll
      for (int dt = 0; dt < 4; dt++){
        int dr = dt * 16 + l15;
        bf16x8 av = *(const bf16x8*)&Vts[dr * 128 + (((ks * 4 + quad) ^ (dr & 15)) << 3)];
        o[dt] = __builtin_amdgcn_mfma_f32_16x16x32_bf16(av, bp, o[dt], 0, 0, 0);
      }
    }
    __syncthreads();   // P + Vts reads done -> next DMA may overwrite
  };

  for (int jt = 0; jt < jt_max; jt++) kv_iter(jt, false);
  kv_iter(jt_max, true);

  lsum += __shfl_xor(lsum, 16);
  lsum += __shfl_xor(lsum, 32);
  float inv = 1.f / lsum;
  const size_t orow = (size_t)((b << 11) + qpos) * 1024 + h * 64;
  #pragma unroll
  for (int dt = 0; dt < 4; dt++){
    ushort4 w;
    w.x = f2bf(o[dt][0] * inv); w.y = f2bf(o[dt][1] * inv);
    w.z = f2bf(o[dt][2] * inv); w.w = f2bf(o[dt][3] * inv);
    *(ushort4*)&Oo[orow + dt * 16 + quad * 4] = w;
  }
}

// ---------------- GEMM2: attn[4096,1024](bf16) @ woutT + b_out -> out (fp32), BK=64 ----------------
__global__ __launch_bounds__(256) void gemm_out(const u16* __restrict__ A,
                                                const u16* __restrict__ Bt,
                                                const float* __restrict__ bias,
                                                float* __restrict__ out){
  __shared__ u16 As[128 * 64];
  __shared__ u16 Bs[128 * 64];
  const int tid = threadIdx.x;
  const int lane = tid & 63, wid = tid >> 6;
  const int l15 = lane & 15, quad = lane >> 4;
  const int wm = wid >> 1, wn = wid & 1;
  const int bid = blockIdx.x;
  const int xcd = bid & 7, t8 = bid >> 3;          // t8 in [0,32)
  const int bm = ((xcd << 2) + (t8 & 3)) << 7;
  const int bn = (t8 >> 2) << 7;                   // [0,1024)

  const int lr = lane >> 3;
  const int cc = (lane & 7) ^ lr;
  const u16* gA0 = A  + (size_t)(bm + wid * 32 + lr) * 1024 + (cc << 3);
  const u16* gB0 = Bt + (size_t)(bn + wid * 32 + lr) * 1024 + (cc << 3);
  u16* lA0 = &As[wid * 2048];
  u16* lB0 = &Bs[wid * 2048];

  f32x4 acc[4][4];
  #pragma unroll
  for (int i = 0; i < 4; i++)
    #pragma unroll
    for (int j = 0; j < 4; j++) acc[i][j] = (f32x4){0.f, 0.f, 0.f, 0.f};

  for (int k0 = 0; k0 < 1024; k0 += 64){
    #pragma unroll
    for (int t = 0; t < 4; t++){
      gl16(gA0 + k0 + t * 8192, lA0 + t * 512);
      gl16(gB0 + k0 + t * 8192, lB0 + t * 512);
    }
    __syncthreads();
    #pragma unroll
    for (int hf = 0; hf < 2; hf++){
      bf16x8 af[4], bfr[4];
      #pragma unroll
      for (int mt = 0; mt < 4; mt++){
        int row = wm * 64 + mt * 16 + l15;
        af[mt] = *(const bf16x8*)&As[row * 64 + (((hf * 4 + quad) ^ (row & 7)) << 3)];
      }
      #pragma unroll
      for (int nt = 0; nt < 4; nt++){
        int row = wn * 64 + nt * 16 + l15;
        bfr[nt] = *(const bf16x8*)&Bs[row * 64 + (((hf * 4 + quad) ^ (row & 7)) << 3)];
      }
      #pragma unroll
      for (int mt = 0; mt < 4; mt++)
        #pragma unroll
        for (int nt = 0; nt < 4; nt++)
          acc[mt][nt] = __builtin_amdgcn_mfma_f32_16x16x32_bf16(bfr[nt], af[mt], acc[mt][nt], 0, 0, 0);
    }
    __syncthreads();
  }

  #pragma unroll
  for (int nt = 0; nt < 4; nt++){
    int c0 = bn + wn * 64 + nt * 16 + quad * 4;    // col base (reg-dim)
    float4 bv = *(const float4*)&bias[c0];
    #pragma unroll
    for (int mt = 0; mt < 4; mt++){
      int row = bm + wm * 64 + mt * 16 + l15;      // row (lane-dim)
      float4 w;
      w.x = acc[mt][nt][0] + bv.x; w.y = acc[mt][nt][1] + bv.y;
      w.z = acc[mt][nt][2] + bv.z; w.w = acc[mt][nt][3] + bv.w;
      *(float4*)&out[(size_t)row * 1024 + c0] = w;
    }
  }
}

extern "C" void kernel_launch(void* const* d_in, const int* in_sizes, int n_in,
                              void* d_out, int out_size, void* d_ws, size_t ws_size,
                              hipStream_t stream){
  const float* x     = (const float*)d_in[0];
  const float* w_qkv = (const float*)d_in[1];
  const float* w_out = (const float*)d_in[2];
  const float* b_out = (const float*)d_in[3];
  float* out = (float*)d_out;

  char* ws = (char*)d_ws;
  u16* xb    = (u16*)(ws);                  // [4096][1024] bf16   8 MB
  u16* wqkvT = (u16*)(ws + (8u  << 20));    // [3072][1024]        6 MB
  u16* woutT = (u16*)(ws + (14u << 20));    // [1024][1024]        2 MB
  u16* Qb    = (u16*)(ws + (16u << 20));    // [2,16,2048,64]      8 MB
  u16* Kb    = (u16*)(ws + (24u << 20));    // 8 MB
  u16* Vtb   = (u16*)(ws + (32u << 20));    // [2,16,64,2048]      8 MB
  u16* attn  = (u16*)(ws + (40u << 20));    // [4096][1024]        8 MB

  prep<<<8192, 256, 0, stream>>>(x, w_qkv, w_out, xb, wqkvT, woutT);
  gemm_qkv<<<768, 256, 0, stream>>>(xb, wqkvT, Qb, Kb, Vtb);
  attn_kernel<<<dim3(1024), 256, 0, stream>>>(Qb, Kb, Vtb, attn);
  gemm_out<<<256, 256, 0, stream>>>(attn, woutT, b_out, out);
}

// Round 12
// 166.765 us; speedup vs baseline: 1.0960x; 1.0557x over previous
//
#include <hip/hip_runtime.h>

typedef __attribute__((ext_vector_type(8))) short bf16x8;
typedef __attribute__((ext_vector_type(4))) float f32x4;
typedef unsigned short u16;
typedef unsigned int u32;

#define SEQ 2048
#define NHEAD 16
#define EXP2_SCALE 0.045084219f  // (1024^-0.5) * log2(e), folded into Q at gemm_qkv epilogue

__device__ __forceinline__ u16 f2bf(float f){
  u32 u = __builtin_bit_cast(u32, f);
  u += 0x7FFFu + ((u >> 16) & 1u);   // RNE
  return (u16)(u >> 16);
}

// async global->LDS, 16B per lane; LDS dest = uniform base + lane*16
__device__ __forceinline__ void gl16(const u16* g, u16* l){
  __builtin_amdgcn_global_load_lds(
      (__attribute__((address_space(1))) void*)(unsigned long long)(const void*)g,
      (__attribute__((address_space(3))) void*)(unsigned)(unsigned long long)(const void*)l,
      16, 0, 0);
}

// ---------------- fused prep: x->bf16, w_qkv^T->bf16, w_out^T->bf16 ----------------
__global__ __launch_bounds__(256) void prep(const float* __restrict__ x,
                                            const float* __restrict__ w_qkv,
                                            const float* __restrict__ w_out,
                                            u16* __restrict__ xb,
                                            u16* __restrict__ wqkvT,
                                            u16* __restrict__ woutT){
  __shared__ u16 t[32][33];
  const int bid = blockIdx.x;
  if (bid < 4096){
    int i = (bid * 256 + threadIdx.x) << 2;
    float4 v = *(const float4*)&x[i];
    ushort4 o;
    o.x = f2bf(v.x); o.y = f2bf(v.y); o.z = f2bf(v.z); o.w = f2bf(v.w);
    *(ushort4*)&xb[i] = o;
    return;
  }
  const float* src; u16* dst; int R, C, bx, by;
  if (bid < 7168){ int tt = bid - 4096; src = w_qkv; dst = wqkvT; R = 1024; C = 3072; bx = tt % 96; by = tt / 96; }
  else           { int tt = bid - 7168; src = w_out; dst = woutT; R = 1024; C = 1024; bx = tt % 32; by = tt / 32; }
  const int c0 = bx << 5, r0 = by << 5;
  const int tx = threadIdx.x & 31, tg = threadIdx.x >> 5;
  #pragma unroll
  for (int i = 0; i < 4; i++){
    int r = (tg << 2) + i;
    t[r][tx] = f2bf(src[(size_t)(r0 + r) * C + (c0 + tx)]);
  }
  __syncthreads();
  #pragma unroll
  for (int i = 0; i < 4; i++){
    int c = (tg << 2) + i;
    dst[(size_t)(c0 + c) * R + (r0 + tx)] = t[tx][c];
  }
}

// LDS addressing for 128x32 bf16 tile: 16B chunk c of row r at slot c^((r>>1)&3)
__device__ __forceinline__ int sw32(int row, int c){
  return row * 32 + (((c ^ ((row >> 1) & 3))) << 3);
}

// ---------------- GEMM1: xb[4096,1024] @ wqkvT -> Q/K/Vt (bf16), BK=32, 32 iters ----------------
__global__ __launch_bounds__(256) void gemm_qkv(const u16* __restrict__ A,
                                                const u16* __restrict__ Bt,
                                                u16* __restrict__ Qo,
                                                u16* __restrict__ Ko,
                                                u16* __restrict__ Vto){
  __shared__ u16 As[128 * 32];   // 8 KB
  __shared__ u16 Bs[128 * 32];
  const int tid = threadIdx.x;
  const int lane = tid & 63, wid = tid >> 6;
  const int l15 = lane & 15, quad = lane >> 4;
  const int wm = wid >> 1, wn = wid & 1;
  const int bid = blockIdx.x;
  const int xcd = bid & 7, t8 = bid >> 3;          // t8 in [0,96)
  const int bm = ((xcd << 2) + (t8 & 3)) << 7;     // M strip
  const int bn = (t8 >> 2) << 7;                   // N strip (outer)
  const int qkv_idx = bn >> 10;

  const int rT = wid * 32 + (lane >> 2);           // t=0 row; +16 for t=1
  const int cT = (lane & 3) ^ ((rT >> 1) & 3);     // invariant under +16
  const u16* gA0 = A  + (size_t)(bm + rT) * 1024 + cT * 8;
  const u16* gB0 = Bt + (size_t)(bn + rT) * 1024 + cT * 8;
  u16* lA0 = &As[wid * 1024];
  u16* lB0 = &Bs[wid * 1024];

  f32x4 acc[4][4];
  #pragma unroll
  for (int i = 0; i < 4; i++)
    #pragma unroll
    for (int j = 0; j < 4; j++) acc[i][j] = (f32x4){0.f, 0.f, 0.f, 0.f};

  for (int k0 = 0; k0 < 1024; k0 += 32){
    gl16(gA0 + k0,            lA0);
    gl16(gA0 + k0 + 16*1024,  lA0 + 512);
    gl16(gB0 + k0,            lB0);
    gl16(gB0 + k0 + 16*1024,  lB0 + 512);
    __syncthreads();
    bf16x8 af[4], bfr[4];
    #pragma unroll
    for (int mt = 0; mt < 4; mt++)
      af[mt] = *(const bf16x8*)&As[sw32(wm * 64 + mt * 16 + l15, quad)];
    #pragma unroll
    for (int nt = 0; nt < 4; nt++)
      bfr[nt] = *(const bf16x8*)&Bs[sw32(wn * 64 + nt * 16 + l15, quad)];
    #pragma unroll
    for (int mt = 0; mt < 4; mt++)
      #pragma unroll
      for (int nt = 0; nt < 4; nt++)   // swapped operands -> transposed C
        acc[mt][nt] = __builtin_amdgcn_mfma_f32_16x16x32_bf16(bfr[nt], af[mt], acc[mt][nt], 0, 0, 0);
    __syncthreads();
  }

  if (qkv_idx != 2){
    const float qs = (qkv_idx == 0) ? EXP2_SCALE : 1.0f;
    u16* dst = (qkv_idx == 0) ? Qo : Ko;
    #pragma unroll
    for (int mt = 0; mt < 4; mt++){
      int xr = bm + wm * 64 + mt * 16 + l15;      // x row (lane-dim)
      int b = xr >> 11, pos = xr & 2047;
      #pragma unroll
      for (int nt = 0; nt < 4; nt++){
        int c0 = bn + wn * 64 + nt * 16 + quad * 4;   // weight col base (reg-dim)
        int head = (c0 & 1023) >> 6, hd0 = c0 & 63;
        size_t bhh = ((size_t)(b * NHEAD + head)) << 17;
        ushort4 w;
        w.x = f2bf(acc[mt][nt][0] * qs); w.y = f2bf(acc[mt][nt][1] * qs);
        w.z = f2bf(acc[mt][nt][2] * qs); w.w = f2bf(acc[mt][nt][3] * qs);
        *(ushort4*)&dst[bhh + ((size_t)pos << 6) + hd0] = w;
      }
    }
  } else {
    #pragma unroll
    for (int mt = 0; mt < 4; mt++){
      int xr = bm + wm * 64 + mt * 16 + l15;
      int b = xr >> 11, pos = xr & 2047;
      #pragma unroll
      for (int nt = 0; nt < 4; nt++){
        #pragma unroll
        for (int r = 0; r < 4; r++){
          int c = bn + wn * 64 + nt * 16 + quad * 4 + r;
          int head = (c & 1023) >> 6, hd_i = c & 63;
          size_t bhh = ((size_t)(b * NHEAD + head)) << 17;
          Vto[bhh + ((size_t)hd_i << 11) + pos] = f2bf(acc[mt][nt][r]);  // V^T [hd][seq]
        }
      }
    }
  }
}

// ---------------- flash attention, causal, S^T form, fixed-base softmax (r11) ----------------
__global__ __launch_bounds__(256) void attn_kernel(const u16* __restrict__ Q,
                                                   const u16* __restrict__ K,
                                                   const u16* __restrict__ Vt,
                                                   u16* __restrict__ Oo){
  __shared__ u16 Ks[128 * 64];       // [kv][d] chunk c at slot c^(row&7); P^T after QK
  __shared__ u16 Vts[64 * 128];      // [d][kv] chunk c at slot c^(row&15)
  const int tid = threadIdx.x;
  const int lane = tid & 63, wid = tid >> 6;
  const int l15 = lane & 15, quad = lane >> 4;
  const int bh = blockIdx.x & 31;
  const int qt = 31 - (blockIdx.x >> 5);     // heavy blocks dispatch first
  const size_t base = ((size_t)bh) << 17;    // (b*16+h)*2048*64
  const int b = bh >> 4, h = bh & 15;

  const u16* qsrc = Q + base + ((size_t)((qt << 6) + wid * 16 + l15) << 6) + quad * 8;
  const bf16x8 bq0 = *(const bf16x8*)qsrc;
  const bf16x8 bq1 = *(const bf16x8*)(qsrc + 32);

  const int rK = wid * 32 + (lane >> 3);
  const int cK = (lane & 7) ^ (rK & 7);
  const u16* gK0 = K + base + ((size_t)rK << 6) + (cK << 3);
  u16* lK = &Ks[wid * 2048];
  const u16* gV[4];
  #pragma unroll
  for (int t = 0; t < 4; t++){
    int rv = wid * 16 + t * 4 + (lane >> 4);
    int cv = (lane & 15) ^ (rv & 15);
    gV[t] = Vt + base + (size_t)rv * 2048 + (cv << 3);
  }
  u16* lV = &Vts[wid * 2048];

  f32x4 o[4];
  #pragma unroll
  for (int dt = 0; dt < 4; dt++) o[dt] = (f32x4){0.f, 0.f, 0.f, 0.f};
  float lsum = 0.f;
  const int qpos = (qt << 6) + wid * 16 + l15;
  const int jt_max = qt >> 1;
  u16* Pw = &Ks[wid * 2048];                 // wave's P^T slice (reuses its Ks quarter)

  auto kv_iter = [&](const int jt, const bool diag) __attribute__((always_inline)) {
    const u16* gk = gK0 + (size_t)jt * 8192;
    #pragma unroll
    for (int t = 0; t < 4; t++) gl16(gk + t * 512, lK + t * 512);
    #pragma unroll
    for (int t = 0; t < 4; t++) gl16(gV[t] + (jt << 7), lV + t * 512);
    __syncthreads();

    f32x4 st[8];
    #pragma unroll
    for (int mt = 0; mt < 8; mt++) st[mt] = (f32x4){0.f, 0.f, 0.f, 0.f};
    #pragma unroll
    for (int mt = 0; mt < 8; mt++){
      int kvr = mt * 16 + l15;
      bf16x8 ak0 = *(const bf16x8*)&Ks[kvr * 64 + ((quad ^ (kvr & 7)) << 3)];
      st[mt] = __builtin_amdgcn_mfma_f32_16x16x32_bf16(ak0, bq0, st[mt], 0, 0, 0);
      bf16x8 ak1 = *(const bf16x8*)&Ks[kvr * 64 + (((4 + quad) ^ (kvr & 7)) << 3)];
      st[mt] = __builtin_amdgcn_mfma_f32_16x16x32_bf16(ak1, bq1, st[mt], 0, 0, 0);
    }
    __syncthreads();   // all waves done reading Ks -> safe to overwrite with P^T

    #pragma unroll
    for (int mt = 0; mt < 8; mt++){
      float pr[4];
      #pragma unroll
      for (int r = 0; r < 4; r++){
        float w = st[mt][r];
        if (diag){
          int kv = (jt << 7) + mt * 16 + quad * 4 + r;
          if (kv > qpos) w = -INFINITY;
        }
        pr[r] = __builtin_amdgcn_exp2f(w);
      }
      lsum += (pr[0] + pr[1]) + (pr[2] + pr[3]);
      u32 a0 = __builtin_bit_cast(u32, pr[0]) + 0x8000u;
      u32 a1 = __builtin_bit_cast(u32, pr[1]) + 0x8000u;
      u32 a2 = __builtin_bit_cast(u32, pr[2]) + 0x8000u;
      u32 a3 = __builtin_bit_cast(u32, pr[3]) + 0x8000u;
      uint2 pk;
      pk.x = __builtin_amdgcn_perm(a1, a0, 0x07060302u);
      pk.y = __builtin_amdgcn_perm(a3, a2, 0x07060302u);
      *(uint2*)&Pw[l15 * 128 + (((mt * 2 + (quad >> 1)) ^ l15) << 3) + ((quad & 1) << 2)] = pk;
    }

    #pragma unroll
    for (int ks = 0; ks < 4; ks++){
      bf16x8 bp = *(const bf16x8*)&Pw[l15 * 128 + (((ks * 4 + quad) ^ l15) << 3)];
      #pragma unroll
      for (int dt = 0; dt < 4; dt++){
        int dr = dt * 16 + l15;
        bf16x8 av = *(const bf16x8*)&Vts[dr * 128 + (((ks * 4 + quad) ^ (dr & 15)) << 3)];
        o[dt] = __builtin_amdgcn_mfma_f32_16x16x32_bf16(av, bp, o[dt], 0, 0, 0);
      }
    }
    __syncthreads();
  };

  for (int jt = 0; jt < jt_max; jt++) kv_iter(jt, false);
  kv_iter(jt_max, true);

  lsum += __shfl_xor(lsum, 16);
  lsum += __shfl_xor(lsum, 32);
  float inv = 1.f / lsum;
  const size_t orow = (size_t)((b << 11) + qpos) * 1024 + h * 64;
  #pragma unroll
  for (int dt = 0; dt < 4; dt++){
    ushort4 w;
    w.x = f2bf(o[dt][0] * inv); w.y = f2bf(o[dt][1] * inv);
    w.z = f2bf(o[dt][2] * inv); w.w = f2bf(o[dt][3] * inv);
    *(ushort4*)&Oo[orow + dt * 16 + quad * 4] = w;
  }
}

// ---------------- GEMM2: attn[4096,1024](bf16) @ woutT + b_out -> out (fp32) ----------------
// 64M x 128N tiles, grid 512 = 2 blocks/CU (was 1). BK=64. Swapped operands -> float4 stores.
__global__ __launch_bounds__(256) void gemm_out(const u16* __restrict__ A,
                                                const u16* __restrict__ Bt,
                                                const float* __restrict__ bias,
                                                float* __restrict__ out){
  __shared__ u16 As[64 * 64];    // 8 KB, chunk c of row r at slot c^(r&7)
  __shared__ u16 Bs[128 * 64];   // 16 KB
  const int tid = threadIdx.x;
  const int lane = tid & 63, wid = tid >> 6;
  const int l15 = lane & 15, quad = lane >> 4;
  const int wx = wid & 1, ww = wid >> 1;           // wave: 32 xrows x 64 wcols
  const int bid = blockIdx.x;
  const int bm = (bid & 63) << 6;                  // 64 M strips
  const int bn = (bid >> 6) << 7;                  // 8 N strips

  const int lr = lane >> 3;
  const int cc = (lane & 7) ^ lr;
  // A: 64 rows, wave covers [wid*16, wid*16+16), 2 DMAs x 8 rows
  const u16* gA0 = A  + (size_t)(bm + wid * 16 + lr) * 1024 + (cc << 3);
  u16* lA0 = &As[wid * 1024];
  // B: 128 rows, wave covers [wid*32, wid*32+32), 4 DMAs x 8 rows
  const u16* gB0 = Bt + (size_t)(bn + wid * 32 + lr) * 1024 + (cc << 3);
  u16* lB0 = &Bs[wid * 2048];

  f32x4 acc[2][4];
  #pragma unroll
  for (int i = 0; i < 2; i++)
    #pragma unroll
    for (int j = 0; j < 4; j++) acc[i][j] = (f32x4){0.f, 0.f, 0.f, 0.f};

  for (int k0 = 0; k0 < 1024; k0 += 64){
    gl16(gA0 + k0,        lA0);
    gl16(gA0 + k0 + 8192, lA0 + 512);
    #pragma unroll
    for (int t = 0; t < 4; t++)
      gl16(gB0 + k0 + t * 8192, lB0 + t * 512);
    __syncthreads();
    #pragma unroll
    for (int hf = 0; hf < 2; hf++){
      bf16x8 af[2], bfr[4];
      #pragma unroll
      for (int xt = 0; xt < 2; xt++){
        int row = wx * 32 + xt * 16 + l15;
        af[xt] = *(const bf16x8*)&As[row * 64 + (((hf * 4 + quad) ^ (row & 7)) << 3)];
      }
      #pragma unroll
      for (int wt = 0; wt < 4; wt++){
        int row = ww * 64 + wt * 16 + l15;
        bfr[wt] = *(const bf16x8*)&Bs[row * 64 + (((hf * 4 + quad) ^ (row & 7)) << 3)];
      }
      #pragma unroll
      for (int xt = 0; xt < 2; xt++)
        #pragma unroll
        for (int wt = 0; wt < 4; wt++)   // swapped: m=wcol(reg), n=xrow(lane)
          acc[xt][wt] = __builtin_amdgcn_mfma_f32_16x16x32_bf16(bfr[wt], af[xt], acc[xt][wt], 0, 0, 0);
    }
    __syncthreads();
  }

  #pragma unroll
  for (int wt = 0; wt < 4; wt++){
    int c0 = bn + ww * 64 + wt * 16 + quad * 4;    // col base (reg-dim)
    float4 bv = *(const float4*)&bias[c0];
    #pragma unroll
    for (int xt = 0; xt < 2; xt++){
      int row = bm + wx * 32 + xt * 16 + l15;      // row (lane-dim)
      float4 w;
      w.x = acc[xt][wt][0] + bv.x; w.y = acc[xt][wt][1] + bv.y;
      w.z = acc[xt][wt][2] + bv.z; w.w = acc[xt][wt][3] + bv.w;
      *(float4*)&out[(size_t)row * 1024 + c0] = w;
    }
  }
}

extern "C" void kernel_launch(void* const* d_in, const int* in_sizes, int n_in,
                              void* d_out, int out_size, void* d_ws, size_t ws_size,
                              hipStream_t stream){
  const float* x     = (const float*)d_in[0];
  const float* w_qkv = (const float*)d_in[1];
  const float* w_out = (const float*)d_in[2];
  const float* b_out = (const float*)d_in[3];
  float* out = (float*)d_out;

  char* ws = (char*)d_ws;
  u16* xb    = (u16*)(ws);                  // [4096][1024] bf16   8 MB
  u16* wqkvT = (u16*)(ws + (8u  << 20));    // [3072][1024]        6 MB
  u16* woutT = (u16*)(ws + (14u << 20));    // [1024][1024]        2 MB
  u16* Qb    = (u16*)(ws + (16u << 20));    // [2,16,2048,64]      8 MB
  u16* Kb    = (u16*)(ws + (24u << 20));    // 8 MB
  u16* Vtb   = (u16*)(ws + (32u << 20));    // [2,16,64,2048]      8 MB
  u16* attn  = (u16*)(ws + (40u << 20));    // [4096][1024]        8 MB

  prep<<<8192, 256, 0, stream>>>(x, w_qkv, w_out, xb, wqkvT, woutT);
  gemm_qkv<<<768, 256, 0, stream>>>(xb, wqkvT, Qb, Kb, Vtb);
  attn_kernel<<<dim3(1024), 256, 0, stream>>>(Qb, Kb, Vtb, attn);
  gemm_out<<<512, 256, 0, stream>>>(attn, woutT, b_out, out);
}